// Round 1
// baseline (7735.207 us; speedup 1.0000x reference)
//
#include <hip/hip_runtime.h>

typedef unsigned int u32;
typedef unsigned short u16;

#define TN 5  // nodes per block in the fused conv+fc kernel

static __device__ __forceinline__ u32 f2bf(float f) {
  u32 u = __float_as_uint(f);
  return (u + 0x7fffu + ((u >> 16) & 1u)) >> 16;  // round-to-nearest-even bf16 bits
}
static __device__ __forceinline__ float bflo(u32 u) { return __uint_as_float(u << 16); }
static __device__ __forceinline__ float bfhi(u32 u) { return __uint_as_float(u & 0xffff0000u); }

// ---------------------------------------------------------------------------
// Fused conv1(6->16,k5,p2)+relu -> conv2(16->32,k5,p2)+relu -> fc(3840->128)
// One block = TN nodes. Convs register-tiled (weights in VGPRs, float4 LDS
// window loads). fc: bf16 weights (pre-converted) + bf16 activations in LDS,
// 8-outputs x 16-k-slices per thread, LDS-atomic reduction.
// ---------------------------------------------------------------------------
__global__ __launch_bounds__(256) void k_convfc(
    const float* __restrict__ ea, const float* __restrict__ w1, const float* __restrict__ b1,
    const float* __restrict__ w2, const float* __restrict__ b2,
    const u32* __restrict__ fcwb, const float* __restrict__ fcb,
    float* __restrict__ xfc, int n)
{
  __shared__ float sW1[480];
  __shared__ float sB1[16];
  __shared__ float sW2[2560];
  __shared__ float sB2[32];
  __shared__ __align__(16) float sX0[6 * 124];    // padded rows: idx = pos+2
  __shared__ __align__(16) float sX1[16 * 132];   // padded rows: idx = pos+2, tail zeros
  __shared__ __align__(16) u16 sX2[TN * 3840];    // bf16 conv2 output
  __shared__ float sOut[TN * 128];

  const int t = threadIdx.x;
  for (int i = t; i < 480; i += 256) sW1[i] = w1[i];
  for (int i = t; i < 2560; i += 256) sW2[i] = w2[i];
  if (t < 16) sB1[t] = b1[t];
  if (t < 32) sB2[t] = b2[t];
  for (int i = t; i < TN * 128; i += 256) sOut[i] = 0.0f;
  __syncthreads();

  // conv1 mapping: channel o1 = t&15 (16 ch), position group pg1 = t>>4 (15 used, 8 pos each)
  const int o1 = t & 15, pg1 = t >> 4;
  float w1r[30];
#pragma unroll
  for (int i = 0; i < 30; ++i) w1r[i] = sW1[o1 * 30 + i];
  const float bias1 = sB1[o1];

  // conv2 mapping: channel o2 = t&31 (32 ch), pg2 = t>>5 (8 groups, 16 pos; last group 8)
  const int o2 = t & 31, pg2 = t >> 5;
  float w2r[80];
#pragma unroll
  for (int i = 0; i < 80; ++i) w2r[i] = sW2[o2 * 80 + i];
  const float bias2 = sB2[o2];

  const long node0 = (long)blockIdx.x * TN;
  u32* sX2u = (u32*)sX2;

  for (int j = 0; j < TN; ++j) {
    const long node = node0 + j;
    __syncthreads();
    // stage x0 with halo padding
    for (int i = t; i < 6 * 124; i += 256) {
      int c = i / 124, p = (i % 124) - 2;
      float v = 0.0f;
      if (p >= 0 && p < 120 && node < n) v = ea[node * 720 + c * 120 + p];
      sX0[i] = v;
    }
    __syncthreads();
    // conv1 + relu -> sX1
    if (pg1 < 15) {
      const int p0 = pg1 * 8;
      float acc[8];
#pragma unroll
      for (int q = 0; q < 8; ++q) acc[q] = bias1;
#pragma unroll
      for (int c = 0; c < 6; ++c) {
        const float4* s4 = (const float4*)&sX0[c * 124 + p0];
        float4 a4 = s4[0], b4 = s4[1], c4 = s4[2];
        float xw[12] = {a4.x, a4.y, a4.z, a4.w, b4.x, b4.y, b4.z, b4.w, c4.x, c4.y, c4.z, c4.w};
#pragma unroll
        for (int q = 0; q < 8; ++q)
#pragma unroll
          for (int k = 0; k < 5; ++k)
            acc[q] = fmaf(w1r[c * 5 + k], xw[q + k], acc[q]);
      }
#pragma unroll
      for (int q = 0; q < 8; ++q) sX1[o1 * 132 + 2 + p0 + q] = fmaxf(acc[q], 0.0f);
    }
    // zero sX1 pads: idx 0,1 and 122..131 of each row
    for (int i = t; i < 16 * 12; i += 256) {
      int c = i / 12, q = i % 12;
      sX1[c * 132 + (q < 2 ? q : q + 120)] = 0.0f;
    }
    __syncthreads();
    // conv2 + relu -> sX2 (bf16)
    {
      const int p0 = pg2 * 16;
      float acc[16];
#pragma unroll
      for (int q = 0; q < 16; ++q) acc[q] = bias2;
#pragma unroll
      for (int c = 0; c < 16; ++c) {
        const float4* s4 = (const float4*)&sX1[c * 132 + p0];
        float4 a4 = s4[0], b4 = s4[1], c4 = s4[2], d4 = s4[3], e4 = s4[4];
        float xw[20] = {a4.x,a4.y,a4.z,a4.w, b4.x,b4.y,b4.z,b4.w, c4.x,c4.y,c4.z,c4.w,
                        d4.x,d4.y,d4.z,d4.w, e4.x,e4.y,e4.z,e4.w};
#pragma unroll
        for (int q = 0; q < 16; ++q)
#pragma unroll
          for (int k = 0; k < 5; ++k)
            acc[q] = fmaf(w2r[c * 5 + k], xw[q + k], acc[q]);
      }
      const int nst = (pg2 == 7) ? 8 : 16;
      const int base = o2 * 120 + p0;  // even
      for (int q = 0; q < nst; q += 2) {
        u32 u = f2bf(fmaxf(acc[q], 0.0f)) | (f2bf(fmaxf(acc[q + 1], 0.0f)) << 16);
        sX2u[j * 1920 + ((base + q) >> 1)] = u;
      }
    }
  }
  __syncthreads();
  // fc: og = t&15 -> 8 consecutive outputs; ks = t>>4 -> k-slice of 240 (30 uint4)
  {
    const int og = t & 15, ks = t >> 4;
    const int obase = og * 8;
    float acc[8][TN];
#pragma unroll
    for (int oo = 0; oo < 8; ++oo)
#pragma unroll
      for (int j = 0; j < TN; ++j) acc[oo][j] = 0.0f;
    const uint4* wq = (const uint4*)fcwb;   // row stride 480 uint4 (3840 bf16)
    const uint4* xq = (const uint4*)sX2;
    for (int s = 0; s < 30; ++s) {
      const int k8 = ks * 30 + s;
      float wv[64];
#pragma unroll
      for (int oo = 0; oo < 8; ++oo) {
        uint4 w = wq[(size_t)(obase + oo) * 480 + k8];
        wv[oo*8+0] = bflo(w.x); wv[oo*8+1] = bfhi(w.x);
        wv[oo*8+2] = bflo(w.y); wv[oo*8+3] = bfhi(w.y);
        wv[oo*8+4] = bflo(w.z); wv[oo*8+5] = bfhi(w.z);
        wv[oo*8+6] = bflo(w.w); wv[oo*8+7] = bfhi(w.w);
      }
#pragma unroll
      for (int j = 0; j < TN; ++j) {
        uint4 x = xq[j * 480 + k8];
        float xv[8] = {bflo(x.x), bfhi(x.x), bflo(x.y), bfhi(x.y),
                       bflo(x.z), bfhi(x.z), bflo(x.w), bfhi(x.w)};
#pragma unroll
        for (int oo = 0; oo < 8; ++oo)
#pragma unroll
          for (int kk = 0; kk < 8; ++kk)
            acc[oo][j] = fmaf(wv[oo*8+kk], xv[kk], acc[oo][j]);
      }
    }
#pragma unroll
    for (int oo = 0; oo < 8; ++oo)
#pragma unroll
      for (int j = 0; j < TN; ++j)
        atomicAdd(&sOut[j * 128 + obase + oo], acc[oo][j]);
  }
  __syncthreads();
  for (int i = t; i < TN * 128; i += 256) {
    long node = node0 + (i >> 7);
    int o = i & 127;
    if (node < n) xfc[node * 128 + o] = sOut[i] + fcb[o];
  }
}

// ---------------------------------------------------------------------------
// GCN dense part: H[i][o] = sum_k act(X[i][k]) * W[o][k]   (W: [128,128] fp32)
// 16 nodes per block; W staged to LDS as bf16 pairs (row stride 66 uints ->
// 2-way-max bank aliasing, free per m136).
// ---------------------------------------------------------------------------
__global__ __launch_bounds__(256) void k_gcn_gemm(
    const float* __restrict__ X, const float* __restrict__ W,
    float* __restrict__ H, int n, int relu)
{
  __shared__ __align__(16) float sX[16 * 132];
  __shared__ __align__(8) u32 sW[128 * 66];
  const int t = threadIdx.x;
  const long node0 = (long)blockIdx.x * 16;
  for (int i = t; i < 8192; i += 256) {
    sW[(i >> 6) * 66 + (i & 63)] = f2bf(W[2 * i]) | (f2bf(W[2 * i + 1]) << 16);
  }
  for (int i = t; i < 2048; i += 256) {
    int j = i >> 7, k = i & 127;
    long node = node0 + j;
    float v = (node < n) ? X[node * 128 + k] : 0.0f;
    if (relu) v = fmaxf(v, 0.0f);
    sX[j * 132 + k] = v;
  }
  __syncthreads();
  const int og = t >> 3, jp = t & 7;  // 32 o-groups x 8 j-pairs
  float acc[4][2];
#pragma unroll
  for (int oo = 0; oo < 4; ++oo) { acc[oo][0] = 0.0f; acc[oo][1] = 0.0f; }
  for (int k = 0; k < 128; k += 4) {
    float wv[16];
#pragma unroll
    for (int oo = 0; oo < 4; ++oo) {
      uint2 wu = *(const uint2*)&sW[(og * 4 + oo) * 66 + (k >> 1)];
      wv[oo*4+0] = bflo(wu.x); wv[oo*4+1] = bfhi(wu.x);
      wv[oo*4+2] = bflo(wu.y); wv[oo*4+3] = bfhi(wu.y);
    }
#pragma unroll
    for (int jj = 0; jj < 2; ++jj) {
      const float4 x4 = *(const float4*)&sX[(jp * 2 + jj) * 132 + k];
#pragma unroll
      for (int oo = 0; oo < 4; ++oo)
        acc[oo][jj] = fmaf(wv[oo*4+0], x4.x, fmaf(wv[oo*4+1], x4.y,
                      fmaf(wv[oo*4+2], x4.z, fmaf(wv[oo*4+3], x4.w, acc[oo][jj]))));
    }
  }
#pragma unroll
  for (int jj = 0; jj < 2; ++jj) {
    long node = node0 + jp * 2 + jj;
    if (node < n) {
#pragma unroll
      for (int oo = 0; oo < 4; ++oo)
        H[node * 128 + og * 4 + oo] = acc[oo][jj];
    }
  }
}

// One wave per (edge or self-loop); symmetric-norm message scatter.
__global__ void k_scatter(const float* __restrict__ Hs, float* __restrict__ Out,
                          const int* __restrict__ src, const int* __restrict__ dst,
                          const float* __restrict__ dinv, int n)
{
  const int gid = blockIdx.x * blockDim.x + threadIdx.x;
  const int widx = gid >> 6;
  const int lane = gid & 63;
  if (widx >= 2 * n) return;
  int s, d;
  if (widx < n) { s = src[widx]; d = dst[widx]; }
  else { s = widx - n; d = s; }
  const float nrm = dinv[s] * dinv[d];
  const float2 v = *(const float2*)(Hs + (size_t)s * 128 + lane * 2);
  float* o = Out + (size_t)d * 128 + lane * 2;
  unsafeAtomicAdd(o, v.x * nrm);
  unsafeAtomicAdd(o + 1, v.y * nrm);
}

__global__ void k_fill1(float* p, int n) {
  int i = blockIdx.x * 256 + threadIdx.x; if (i < n) p[i] = 1.0f;
}
__global__ void k_deg(float* dinv, const int* __restrict__ dst, int n) {
  int i = blockIdx.x * 256 + threadIdx.x; if (i < n) unsafeAtomicAdd(&dinv[dst[i]], 1.0f);
}
__global__ void k_rsqrt(float* p, int n) {
  int i = blockIdx.x * 256 + threadIdx.x; if (i < n) p[i] = rsqrtf(p[i]);
}
__global__ void k_bias_init(float* __restrict__ p, const float* __restrict__ b, int n) {
  int i = blockIdx.x * 256 + threadIdx.x; if (i < n * 128) p[i] = b[i & 127];
}
__global__ void k_cvt_fcw(const float* __restrict__ w, u32* __restrict__ wb, int nu) {
  int i = blockIdx.x * 256 + threadIdx.x;
  if (i < nu) wb[i] = f2bf(w[2 * i]) | (f2bf(w[2 * i + 1]) << 16);
}
__global__ void k_zero(float* p, int n) {
  int i = blockIdx.x * 256 + threadIdx.x; if (i < n) p[i] = 0.0f;
}

// LDS-staged pooling: pooled[batch[src[e]]] += X[e]
__global__ __launch_bounds__(256) void k_pool(const float* __restrict__ X,
    const int* __restrict__ src, const int* __restrict__ batch,
    float* __restrict__ pooled, int n)
{
  __shared__ float sAcc[64 * 128];
  for (int i = threadIdx.x; i < 8192; i += 256) sAcc[i] = 0.0f;
  __syncthreads();
  const int c = threadIdx.x & 127, half = threadIdx.x >> 7;
  for (int e = blockIdx.x * 2 + half; e < n; e += gridDim.x * 2) {
    int g = batch[src[e]];
    atomicAdd(&sAcc[g * 128 + c], X[(size_t)e * 128 + c]);
  }
  __syncthreads();
  for (int i = threadIdx.x; i < 8192; i += 256) unsafeAtomicAdd(&pooled[i], sAcc[i]);
}

// Final MLP head: relu(pooled @ fc1.T + b1) @ fc2.T + b2  (one block per graph)
__global__ __launch_bounds__(256) void k_mlp(const float* __restrict__ pooled,
    const float* __restrict__ f1w, const float* __restrict__ f1b,
    const float* __restrict__ f2w, const float* __restrict__ f2b,
    float* __restrict__ out)
{
  const int g = blockIdx.x, t = threadIdx.x;
  __shared__ float sP[128];
  __shared__ float sY[256];
  if (t < 128) sP[t] = pooled[g * 128 + t];
  __syncthreads();
  {
    const float* w = f1w + (size_t)t * 128;
    float a = f1b[t];
    for (int k = 0; k < 128; k += 4) {
      float4 w4 = *(const float4*)(w + k);
      a = fmaf(w4.x, sP[k], fmaf(w4.y, sP[k+1], fmaf(w4.z, sP[k+2], fmaf(w4.w, sP[k+3], a))));
    }
    sY[t] = fmaxf(a, 0.0f);
  }
  __syncthreads();
  if (t < 128) {
    const float* w = f2w + (size_t)t * 256;
    float a = f2b[t];
    for (int k = 0; k < 256; k += 4) {
      float4 w4 = *(const float4*)(w + k);
      a = fmaf(w4.x, sY[k], fmaf(w4.y, sY[k+1], fmaf(w4.z, sY[k+2], fmaf(w4.w, sY[k+3], a))));
    }
    out[g * 128 + t] = a;
  }
}

extern "C" void kernel_launch(void* const* d_in, const int* in_sizes, int n_in,
                              void* d_out, int out_size, void* d_ws, size_t ws_size,
                              hipStream_t stream) {
  const float* ea  = (const float*)d_in[0];
  const int* eidx  = (const int*)d_in[1];
  const int* batch = (const int*)d_in[2];
  const float* w1  = (const float*)d_in[4];
  const float* b1  = (const float*)d_in[5];
  const float* w2  = (const float*)d_in[6];
  const float* b2  = (const float*)d_in[7];
  const float* fcw = (const float*)d_in[8];
  const float* fcb = (const float*)d_in[9];
  const float* g1w = (const float*)d_in[10];
  const float* g1b = (const float*)d_in[11];
  const float* g2w = (const float*)d_in[12];
  const float* g2b = (const float*)d_in[13];
  const float* f1w = (const float*)d_in[14];
  const float* f1b = (const float*)d_in[15];
  const float* f2w = (const float*)d_in[16];
  const float* f2b = (const float*)d_in[17];

  const int n = in_sizes[0] / 720;   // 100000
  const int* src = eidx;             // edge_index[0]
  const int* dst = eidx + n;         // edge_index[1]

  // workspace layout (~155 MB)
  float* A      = (float*)d_ws;                 // [n,128] fc output / gcn2 gemm out
  float* B      = A + (size_t)n * 128;          // [n,128] gcn1 gemm out / gcn2 acc
  float* C      = B + (size_t)n * 128;          // [n,128] gcn1 acc
  float* dinv   = C + (size_t)n * 128;          // [n]
  float* pooled = dinv + n;                     // [64,128]
  u32*  fcwb    = (u32*)(pooled + 64 * 128);    // fc_w in bf16 pairs (245760 u32)

  const int nb_n = (n + 255) / 256;
  k_cvt_fcw<<<(245760 + 255) / 256, 256, 0, stream>>>(fcw, fcwb, 245760);
  k_fill1<<<nb_n, 256, 0, stream>>>(dinv, n);
  k_deg<<<nb_n, 256, 0, stream>>>(dinv, dst, n);
  k_rsqrt<<<nb_n, 256, 0, stream>>>(dinv, n);

  k_convfc<<<(n + TN - 1) / TN, 256, 0, stream>>>(ea, w1, b1, w2, b2, fcwb, fcb, A, n);

  k_bias_init<<<(n * 128 + 255) / 256, 256, 0, stream>>>(C, g1b, n);
  k_gcn_gemm<<<(n + 15) / 16, 256, 0, stream>>>(A, g1w, B, n, 0);
  k_scatter<<<(2 * n * 64 + 255) / 256, 256, 0, stream>>>(B, C, src, dst, dinv, n);

  k_gcn_gemm<<<(n + 15) / 16, 256, 0, stream>>>(C, g2w, A, n, 1);
  k_bias_init<<<(n * 128 + 255) / 256, 256, 0, stream>>>(B, g2b, n);
  k_scatter<<<(2 * n * 64 + 255) / 256, 256, 0, stream>>>(A, B, src, dst, dinv, n);

  k_zero<<<(8192 + 255) / 256, 256, 0, stream>>>(pooled, 8192);
  k_pool<<<256, 256, 0, stream>>>(B, src, batch, pooled, n);
  k_mlp<<<64, 256, 0, stream>>>(pooled, f1w, f1b, f2w, f2b, (float*)d_out);
}

// Round 2
// 3657.999 us; speedup vs baseline: 2.1146x; 2.1146x over previous
//
#include <hip/hip_runtime.h>

typedef unsigned int u32;
typedef unsigned short u16;
typedef short short8 __attribute__((ext_vector_type(8)));   // 8 x bf16 (4 VGPRs)
typedef float floatx4 __attribute__((ext_vector_type(4)));  // MFMA accumulator

static __device__ __forceinline__ u32 f2bf(float f) {
  u32 u = __float_as_uint(f);
  return (u + 0x7fffu + ((u >> 16) & 1u)) >> 16;  // round-to-nearest-even bf16 bits
}
static __device__ __forceinline__ float bflo(u32 u) { return __uint_as_float(u << 16); }
static __device__ __forceinline__ float bfhi(u32 u) { return __uint_as_float(u & 0xffff0000u); }

// ---------------------------------------------------------------------------
// Persistent fused kernel: conv1(6->16,k5,p2)+relu -> conv2(16->32,k5,p2)+relu
// -> fc(3840->128) via MFMA.
// Grid = 768 blocks x 256 thr; each block grid-strides over 16-node tiles.
// conv2 writes bf16 X2 [16 x 3840] to a PRIVATE per-block global slab
// (aliases B/C workspace, dead during this kernel). fc phase: 4 waves x
// 2 n-tiles of 16 outputs, A-frags from slab (L2-hot), B-frags from
// pre-swizzled fcw (coalesced 1KB per wave-load).
// ---------------------------------------------------------------------------
__global__ __launch_bounds__(256) void k_convfc(
    const float* __restrict__ ea, const float* __restrict__ w1, const float* __restrict__ b1,
    const float* __restrict__ w2, const float* __restrict__ b2,
    const u32* __restrict__ fcwsw, const float* __restrict__ fcb,
    u16* __restrict__ slab_base, float* __restrict__ xfc, int n, int ntiles)
{
  __shared__ float sW1[480];
  __shared__ float sB1[16];
  __shared__ float sW2[2560];
  __shared__ float sB2[32];
  __shared__ __align__(16) float sX0[6 * 124];    // padded rows: idx = pos+2
  __shared__ __align__(16) float sX1[16 * 132];   // padded rows: idx = pos+2

  const int t = threadIdx.x;
  for (int i = t; i < 480; i += 256) sW1[i] = w1[i];
  for (int i = t; i < 2560; i += 256) sW2[i] = w2[i];
  if (t < 16) sB1[t] = b1[t];
  if (t < 32) sB2[t] = b2[t];
  // zero sX1 pad columns once (conv1 only ever writes cols 2..121)
  for (int i = t; i < 16 * 12; i += 256) {
    int c = i / 12, q = i % 12;
    sX1[c * 132 + (q < 2 ? q : q + 120)] = 0.0f;
  }
  __syncthreads();

  // conv1 mapping: o1 = t&15 (16 ch), pg1 = t>>4 (15 groups x 8 pos)
  const int o1 = t & 15, pg1 = t >> 4;
  float w1r[30];
#pragma unroll
  for (int i = 0; i < 30; ++i) w1r[i] = sW1[o1 * 30 + i];
  const float bias1 = sB1[o1];

  // conv2 mapping: o2 = t&31 (32 ch), pg2 = t>>5 (8 groups x 16 pos; last 8)
  const int o2 = t & 31, pg2 = t >> 5;
  float w2r[80];
#pragma unroll
  for (int i = 0; i < 80; ++i) w2r[i] = sW2[o2 * 80 + i];
  const float bias2 = sB2[o2];

  u16* myslab = slab_base + (size_t)blockIdx.x * (16 * 3840);
  u32* myslab32 = (u32*)myslab;

  const int lane = t & 63, wv = t >> 6;          // 4 waves
  const int quad = lane >> 4, lr = lane & 15;

  for (int tile = blockIdx.x; tile < ntiles; tile += gridDim.x) {
    const long node0 = (long)tile * 16;
    // ---------------- conv phase: one node at a time ----------------
    for (int j = 0; j < 16; ++j) {
      const long node = node0 + j;
      __syncthreads();  // protect sX0/sX1 reuse
      for (int i = t; i < 6 * 124; i += 256) {
        int c = i / 124, p = (i % 124) - 2;
        float v = 0.0f;
        if (p >= 0 && p < 120 && node < n) v = ea[node * 720 + c * 120 + p];
        sX0[i] = v;
      }
      __syncthreads();
      // conv1 + relu -> sX1
      if (pg1 < 15) {
        const int p0 = pg1 * 8;
        float acc[8];
#pragma unroll
        for (int q = 0; q < 8; ++q) acc[q] = bias1;
#pragma unroll
        for (int c = 0; c < 6; ++c) {
          const float4* s4 = (const float4*)&sX0[c * 124 + p0];
          float4 a4 = s4[0], b4 = s4[1], c4 = s4[2];
          float xw[12] = {a4.x, a4.y, a4.z, a4.w, b4.x, b4.y, b4.z, b4.w, c4.x, c4.y, c4.z, c4.w};
#pragma unroll
          for (int q = 0; q < 8; ++q)
#pragma unroll
            for (int k = 0; k < 5; ++k)
              acc[q] = fmaf(w1r[c * 5 + k], xw[q + k], acc[q]);
        }
#pragma unroll
        for (int q = 0; q < 8; ++q) sX1[o1 * 132 + 2 + p0 + q] = fmaxf(acc[q], 0.0f);
      }
      __syncthreads();
      // conv2 + relu -> bf16 slab (global)
      {
        const int p0 = pg2 * 16;
        float acc[16];
#pragma unroll
        for (int q = 0; q < 16; ++q) acc[q] = bias2;
#pragma unroll
        for (int c = 0; c < 16; ++c) {
          const float4* s4 = (const float4*)&sX1[c * 132 + p0];
          float4 a4 = s4[0], b4 = s4[1], c4 = s4[2], d4 = s4[3], e4 = s4[4];
          float xw[20] = {a4.x,a4.y,a4.z,a4.w, b4.x,b4.y,b4.z,b4.w, c4.x,c4.y,c4.z,c4.w,
                          d4.x,d4.y,d4.z,d4.w, e4.x,e4.y,e4.z,e4.w};
#pragma unroll
          for (int q = 0; q < 16; ++q)
#pragma unroll
            for (int k = 0; k < 5; ++k)
              acc[q] = fmaf(w2r[c * 5 + k], xw[q + k], acc[q]);
        }
        u32 pk[8];
#pragma unroll
        for (int q = 0; q < 8; ++q)
          pk[q] = f2bf(fmaxf(acc[2 * q], 0.0f)) | (f2bf(fmaxf(acc[2 * q + 1], 0.0f)) << 16);
        const int bu = j * 1920 + o2 * 60 + pg2 * 8;  // u32 index, 16B aligned
        uint4* dstq = (uint4*)(myslab32 + bu);
        dstq[0] = make_uint4(pk[0], pk[1], pk[2], pk[3]);
        if (pg2 != 7) dstq[1] = make_uint4(pk[4], pk[5], pk[6], pk[7]);
      }
    }
    __syncthreads();  // slab writes drained (vmcnt0 before barrier) & visible

    // ---------------- fc phase: MFMA ----------------
    // wave wv handles output n-tiles wv and wv+4.
    {
      const int c0 = wv * 16 + lr;
      const int c1 = (wv + 4) * 16 + lr;
      const float bv0 = fcb[c0], bv1 = fcb[c1];
      floatx4 acc0 = {bv0, bv0, bv0, bv0};
      floatx4 acc1 = {bv1, bv1, bv1, bv1};
      const u16* aPtr = myslab + (size_t)lr * 3840 + quad * 8;  // A: m=lane&15, k=quad*8+j
      const short8* bw = (const short8*)fcwsw;
      const short8* b0p = bw + ((size_t)wv * 120) * 64 + lane;
      const short8* b1p = bw + ((size_t)(wv + 4) * 120) * 64 + lane;
#pragma unroll 2
      for (int ks = 0; ks < 120; ++ks) {
        short8 a = *(const short8*)(aPtr + ks * 32);
        short8 b0 = b0p[ks * 64];
        short8 b1 = b1p[ks * 64];
        acc0 = __builtin_amdgcn_mfma_f32_16x16x32_bf16(a, b0, acc0, 0, 0, 0);
        acc1 = __builtin_amdgcn_mfma_f32_16x16x32_bf16(a, b1, acc1, 0, 0, 0);
      }
      // C/D: col = lane&15, row(node) = quad*4 + reg
#pragma unroll
      for (int r = 0; r < 4; ++r) {
        long node = node0 + quad * 4 + r;
        if (node < n) {
          xfc[node * 128 + c0] = acc0[r];
          xfc[node * 128 + c1] = acc1[r];
        }
      }
    }
  }
}

// Swizzle fc_w [128][3840] fp32 -> bf16 B-fragment-major layout:
// out[((nt*120 + ks)*64 + lane)] (uint4 = 8 bf16), element j =
//   fcw[nt*16 + (lane&15)][ks*32 + ((lane>>4)&3)*8 + j]
__global__ void k_cvt_fcw_sw(const float* __restrict__ fcw, uint4* __restrict__ out) {
  int gid = blockIdx.x * 256 + threadIdx.x;
  if (gid >= 8 * 120 * 64) return;
  int lane = gid & 63, tmp = gid >> 6;
  int ks = tmp % 120, nt = tmp / 120;
  int row = nt * 16 + (lane & 15);
  int k0 = ks * 32 + ((lane >> 4) & 3) * 8;
  const float* p = fcw + (size_t)row * 3840 + k0;
  float4 f0 = *(const float4*)p;
  float4 f1 = *(const float4*)(p + 4);
  uint4 o;
  o.x = f2bf(f0.x) | (f2bf(f0.y) << 16);
  o.y = f2bf(f0.z) | (f2bf(f0.w) << 16);
  o.z = f2bf(f1.x) | (f2bf(f1.y) << 16);
  o.w = f2bf(f1.z) | (f2bf(f1.w) << 16);
  out[gid] = o;
}

// ---------------------------------------------------------------------------
// GCN dense part: H[i][o] = sum_k act(X[i][k]) * W[o][k]   (W: [128,128] fp32)
// ---------------------------------------------------------------------------
__global__ __launch_bounds__(256) void k_gcn_gemm(
    const float* __restrict__ X, const float* __restrict__ W,
    float* __restrict__ H, int n, int relu)
{
  __shared__ __align__(16) float sX[16 * 132];
  __shared__ __align__(8) u32 sW[128 * 66];
  const int t = threadIdx.x;
  const long node0 = (long)blockIdx.x * 16;
  for (int i = t; i < 8192; i += 256) {
    sW[(i >> 6) * 66 + (i & 63)] = f2bf(W[2 * i]) | (f2bf(W[2 * i + 1]) << 16);
  }
  for (int i = t; i < 2048; i += 256) {
    int j = i >> 7, k = i & 127;
    long node = node0 + j;
    float v = (node < n) ? X[node * 128 + k] : 0.0f;
    if (relu) v = fmaxf(v, 0.0f);
    sX[j * 132 + k] = v;
  }
  __syncthreads();
  const int og = t >> 3, jp = t & 7;  // 32 o-groups x 8 j-pairs
  float acc[4][2];
#pragma unroll
  for (int oo = 0; oo < 4; ++oo) { acc[oo][0] = 0.0f; acc[oo][1] = 0.0f; }
  for (int k = 0; k < 128; k += 4) {
    float wv[16];
#pragma unroll
    for (int oo = 0; oo < 4; ++oo) {
      uint2 wu = *(const uint2*)&sW[(og * 4 + oo) * 66 + (k >> 1)];
      wv[oo*4+0] = bflo(wu.x); wv[oo*4+1] = bfhi(wu.x);
      wv[oo*4+2] = bflo(wu.y); wv[oo*4+3] = bfhi(wu.y);
    }
#pragma unroll
    for (int jj = 0; jj < 2; ++jj) {
      const float4 x4 = *(const float4*)&sX[(jp * 2 + jj) * 132 + k];
#pragma unroll
      for (int oo = 0; oo < 4; ++oo)
        acc[oo][jj] = fmaf(wv[oo*4+0], x4.x, fmaf(wv[oo*4+1], x4.y,
                      fmaf(wv[oo*4+2], x4.z, fmaf(wv[oo*4+3], x4.w, acc[oo][jj]))));
    }
  }
#pragma unroll
  for (int jj = 0; jj < 2; ++jj) {
    long node = node0 + jp * 2 + jj;
    if (node < n) {
#pragma unroll
      for (int oo = 0; oo < 4; ++oo)
        H[node * 128 + og * 4 + oo] = acc[oo][jj];
    }
  }
}

// One wave per (edge or self-loop); symmetric-norm message scatter.
__global__ void k_scatter(const float* __restrict__ Hs, float* __restrict__ Out,
                          const int* __restrict__ src, const int* __restrict__ dst,
                          const float* __restrict__ dinv, int n)
{
  const int gid = blockIdx.x * blockDim.x + threadIdx.x;
  const int widx = gid >> 6;
  const int lane = gid & 63;
  if (widx >= 2 * n) return;
  int s, d;
  if (widx < n) { s = src[widx]; d = dst[widx]; }
  else { s = widx - n; d = s; }
  const float nrm = dinv[s] * dinv[d];
  const float2 v = *(const float2*)(Hs + (size_t)s * 128 + lane * 2);
  float* o = Out + (size_t)d * 128 + lane * 2;
  unsafeAtomicAdd(o, v.x * nrm);
  unsafeAtomicAdd(o + 1, v.y * nrm);
}

__global__ void k_fill1(float* p, int n) {
  int i = blockIdx.x * 256 + threadIdx.x; if (i < n) p[i] = 1.0f;
}
__global__ void k_deg(float* dinv, const int* __restrict__ dst, int n) {
  int i = blockIdx.x * 256 + threadIdx.x; if (i < n) unsafeAtomicAdd(&dinv[dst[i]], 1.0f);
}
__global__ void k_rsqrt(float* p, int n) {
  int i = blockIdx.x * 256 + threadIdx.x; if (i < n) p[i] = rsqrtf(p[i]);
}
__global__ void k_bias_init(float* __restrict__ p, const float* __restrict__ b, int n) {
  int i = blockIdx.x * 256 + threadIdx.x; if (i < n * 128) p[i] = b[i & 127];
}
__global__ void k_zero(float* p, int n) {
  int i = blockIdx.x * 256 + threadIdx.x; if (i < n) p[i] = 0.0f;
}

// LDS-staged pooling: pooled[batch[src[e]]] += X[e]
__global__ __launch_bounds__(256) void k_pool(const float* __restrict__ X,
    const int* __restrict__ src, const int* __restrict__ batch,
    float* __restrict__ pooled, int n)
{
  __shared__ float sAcc[64 * 128];
  for (int i = threadIdx.x; i < 8192; i += 256) sAcc[i] = 0.0f;
  __syncthreads();
  const int c = threadIdx.x & 127, half = threadIdx.x >> 7;
  for (int e = blockIdx.x * 2 + half; e < n; e += gridDim.x * 2) {
    int g = batch[src[e]];
    atomicAdd(&sAcc[g * 128 + c], X[(size_t)e * 128 + c]);
  }
  __syncthreads();
  for (int i = threadIdx.x; i < 8192; i += 256) unsafeAtomicAdd(&pooled[i], sAcc[i]);
}

// Final MLP head: relu(pooled @ fc1.T + b1) @ fc2.T + b2  (one block per graph)
__global__ __launch_bounds__(256) void k_mlp(const float* __restrict__ pooled,
    const float* __restrict__ f1w, const float* __restrict__ f1b,
    const float* __restrict__ f2w, const float* __restrict__ f2b,
    float* __restrict__ out)
{
  const int g = blockIdx.x, t = threadIdx.x;
  __shared__ float sP[128];
  __shared__ float sY[256];
  if (t < 128) sP[t] = pooled[g * 128 + t];
  __syncthreads();
  {
    const float* w = f1w + (size_t)t * 128;
    float a = f1b[t];
    for (int k = 0; k < 128; k += 4) {
      float4 w4 = *(const float4*)(w + k);
      a = fmaf(w4.x, sP[k], fmaf(w4.y, sP[k+1], fmaf(w4.z, sP[k+2], fmaf(w4.w, sP[k+3], a))));
    }
    sY[t] = fmaxf(a, 0.0f);
  }
  __syncthreads();
  if (t < 128) {
    const float* w = f2w + (size_t)t * 256;
    float a = f2b[t];
    for (int k = 0; k < 256; k += 4) {
      float4 w4 = *(const float4*)(w + k);
      a = fmaf(w4.x, sY[k], fmaf(w4.y, sY[k+1], fmaf(w4.z, sY[k+2], fmaf(w4.w, sY[k+3], a))));
    }
    out[g * 128 + t] = a;
  }
}

extern "C" void kernel_launch(void* const* d_in, const int* in_sizes, int n_in,
                              void* d_out, int out_size, void* d_ws, size_t ws_size,
                              hipStream_t stream) {
  const float* ea  = (const float*)d_in[0];
  const int* eidx  = (const int*)d_in[1];
  const int* batch = (const int*)d_in[2];
  const float* w1  = (const float*)d_in[4];
  const float* b1  = (const float*)d_in[5];
  const float* w2  = (const float*)d_in[6];
  const float* b2  = (const float*)d_in[7];
  const float* fcw = (const float*)d_in[8];
  const float* fcb = (const float*)d_in[9];
  const float* g1w = (const float*)d_in[10];
  const float* g1b = (const float*)d_in[11];
  const float* g2w = (const float*)d_in[12];
  const float* g2b = (const float*)d_in[13];
  const float* f1w = (const float*)d_in[14];
  const float* f1b = (const float*)d_in[15];
  const float* f2w = (const float*)d_in[16];
  const float* f2b = (const float*)d_in[17];

  const int n = in_sizes[0] / 720;   // 100000
  const int* src = eidx;             // edge_index[0]
  const int* dst = eidx + n;         // edge_index[1]

  // workspace layout (~155 MB, same footprint as round 0)
  float* A      = (float*)d_ws;                 // [n,128] fc output / gcn2 gemm out
  float* B      = A + (size_t)n * 128;          // [n,128] gcn1 gemm out / gcn2 acc
  float* C      = B + (size_t)n * 128;          // [n,128] gcn1 acc
  float* dinv   = C + (size_t)n * 128;          // [n]
  float* pooled = dinv + n;                     // [64,128]
  u32*  fcwsw   = (u32*)(pooled + 64 * 128);    // swizzled bf16 fc_w (245760 u32)
  // per-block conv2 slabs alias B+C (dead during k_convfc):
  // 768 blocks x 16*3840 bf16 = 94.4 MB <= 102.4 MB
  u16* slab = (u16*)B;

  const int nb_n = (n + 255) / 256;
  const int ntiles = (n + 15) / 16;
  k_cvt_fcw_sw<<<(61440 + 255) / 256, 256, 0, stream>>>(fcw, (uint4*)fcwsw);
  k_fill1<<<nb_n, 256, 0, stream>>>(dinv, n);
  k_deg<<<nb_n, 256, 0, stream>>>(dinv, dst, n);
  k_rsqrt<<<nb_n, 256, 0, stream>>>(dinv, n);

  k_convfc<<<768, 256, 0, stream>>>(ea, w1, b1, w2, b2, fcwsw, fcb, slab, A, n, ntiles);

  k_bias_init<<<(n * 128 + 255) / 256, 256, 0, stream>>>(C, g1b, n);
  k_gcn_gemm<<<(n + 15) / 16, 256, 0, stream>>>(A, g1w, B, n, 0);
  k_scatter<<<(2 * n * 64 + 255) / 256, 256, 0, stream>>>(B, C, src, dst, dinv, n);

  k_gcn_gemm<<<(n + 15) / 16, 256, 0, stream>>>(C, g2w, A, n, 1);
  k_bias_init<<<(n * 128 + 255) / 256, 256, 0, stream>>>(B, g2b, n);
  k_scatter<<<(2 * n * 64 + 255) / 256, 256, 0, stream>>>(A, B, src, dst, dinv, n);

  k_zero<<<(8192 + 255) / 256, 256, 0, stream>>>(pooled, 8192);
  k_pool<<<256, 256, 0, stream>>>(B, src, batch, pooled, n);
  k_mlp<<<64, 256, 0, stream>>>(pooled, f1w, f1b, f2w, f2b, (float*)d_out);
}

// Round 3
// 2091.696 us; speedup vs baseline: 3.6981x; 1.7488x over previous
//
#include <hip/hip_runtime.h>

typedef unsigned int u32;
typedef unsigned short u16;
typedef short short8 __attribute__((ext_vector_type(8)));   // 8 x bf16 (4 VGPRs)
typedef float floatx4 __attribute__((ext_vector_type(4)));  // MFMA accumulator

static __device__ __forceinline__ u32 f2bf(float f) {
  u32 u = __float_as_uint(f);
  return (u + 0x7fffu + ((u >> 16) & 1u)) >> 16;  // round-to-nearest-even bf16 bits
}
static __device__ __forceinline__ float bflo(u32 u) { return __uint_as_float(u << 16); }
static __device__ __forceinline__ float bfhi(u32 u) { return __uint_as_float(u & 0xffff0000u); }

// ---------------------------------------------------------------------------
// Persistent fused kernel: conv1(6->16,k5,p2)+relu -> conv2(16->32,k5,p2)+relu
// -> fc(3840->128) via MFMA.  768 blocks x 256 thr, grid-stride over 16-node
// tiles. CONV PHASE IS WAVE-SYNCHRONOUS: each wave owns 4 nodes and a private
// LDS region (x0: 744 f, x1: 16x132 f), so no __syncthreads inside the conv
// loop (same-wave ds_write->ds_read ordered by compiler lgkmcnt). Only 2
// barriers per tile (slab-reuse + conv->fc). conv2 output goes bf16 to a
// per-block global slab; fc reads A-frags from it (L2-mostly) and B-frags
// from pre-swizzled bf16 fc_w.
// ---------------------------------------------------------------------------
__global__ __launch_bounds__(256, 3) void k_convfc(
    const float* __restrict__ ea, const float* __restrict__ w1, const float* __restrict__ b1,
    const float* __restrict__ w2, const float* __restrict__ b2,
    const u32* __restrict__ fcwsw, const float* __restrict__ fcb,
    u16* __restrict__ slab_base, float* __restrict__ xfc, int n, int ntiles)
{
  __shared__ __align__(16) float sX0[4][744];    // per-wave, halo: x0[c*124 + p+2]
  __shared__ __align__(16) float sX1[4][2112];   // per-wave, 16 rows x 132 (halo +2)

  const int t = threadIdx.x, lane = t & 63, wv = t >> 6;
  float* __restrict__ x0 = sX0[wv];
  float* __restrict__ x1 = sX1[wv];

  // zero x1 halo pads once (conv1 only writes cols 2..121 of each row)
  for (int i = lane; i < 16 * 12; i += 64) {
    int c = i / 12, q = i % 12;
    x1[c * 132 + (q < 2 ? q : q + 120)] = 0.0f;
  }

  // conv1 mapping: o1 = lane&15 (16 ch), pg1 = lane>>4 -> chunks m = pg1+4i (8 pos each)
  const int o1 = lane & 15, pg1 = lane >> 4;
  float w1r[30];
#pragma unroll
  for (int i = 0; i < 30; ++i) w1r[i] = w1[o1 * 30 + i];
  const float bias1 = b1[o1];

  // conv2 mapping: o2 = lane&31 (32 ch), pg2 = lane>>5 -> chunks m = pg2+2i (12 pos each)
  const int o2 = lane & 31, pg2 = lane >> 5;
  float w2r[80];
#pragma unroll
  for (int i = 0; i < 80; ++i) w2r[i] = w2[o2 * 80 + i];
  const float bias2 = b2[o2];

  u16* myslab = slab_base + (size_t)blockIdx.x * (16 * 3840);
  u32* myslab32 = (u32*)myslab;

  const int quad = lane >> 4, lr = lane & 15;
  const int c0 = wv * 16 + lr;
  const int c1 = (wv + 4) * 16 + lr;
  const float bv0 = fcb[c0], bv1 = fcb[c1];
  const short8* bw = (const short8*)fcwsw;
  const short8* b0p = bw + ((size_t)wv * 120) * 64 + lane;
  const short8* b1p = bw + ((size_t)(wv + 4) * 120) * 64 + lane;

  for (int tile = blockIdx.x; tile < ntiles; tile += gridDim.x) {
    const long node0 = (long)tile * 16;
    __syncthreads();  // prior fc reads of slab complete before overwrite

    // ---------------- conv phase: wave-private, 4 nodes per wave ----------------
    for (int jj = 0; jj < 4; ++jj) {
      const long node = node0 + wv * 4 + jj;
      // stage x0 (wave-local, halo-padded)
      for (int i = lane; i < 744; i += 64) {
        int c = i / 124, p = (i % 124) - 2;
        float v = 0.0f;
        if (p >= 0 && p < 120 && node < n) v = ea[node * 720 + c * 120 + p];
        x0[i] = v;
      }
      // conv1 + relu -> x1 (chunks of 8 positions)
      for (int mi = 0; mi < 4; ++mi) {
        const int m = pg1 + 4 * mi;
        if (m < 15) {
          const int p0 = m * 8;
          float acc[8];
#pragma unroll
          for (int q = 0; q < 8; ++q) acc[q] = bias1;
#pragma unroll
          for (int c = 0; c < 6; ++c) {
            const float4* s4 = (const float4*)&x0[c * 124 + p0];
            float4 a4 = s4[0], b4 = s4[1], c4 = s4[2];
            float xw[12] = {a4.x, a4.y, a4.z, a4.w, b4.x, b4.y, b4.z, b4.w,
                            c4.x, c4.y, c4.z, c4.w};
#pragma unroll
            for (int q = 0; q < 8; ++q)
#pragma unroll
              for (int k = 0; k < 5; ++k)
                acc[q] = fmaf(w1r[c * 5 + k], xw[q + k], acc[q]);
          }
          float2* d2 = (float2*)&x1[o1 * 132 + 2 + p0];
#pragma unroll
          for (int q = 0; q < 4; ++q)
            d2[q] = make_float2(fmaxf(acc[2 * q], 0.0f), fmaxf(acc[2 * q + 1], 0.0f));
        }
      }
      // conv2 + relu -> bf16 slab (chunks of 12 positions)
      for (int mi = 0; mi < 5; ++mi) {
        const int m = pg2 + 2 * mi;
        const int p0 = m * 12;
        float acc[12];
#pragma unroll
        for (int q = 0; q < 12; ++q) acc[q] = bias2;
#pragma unroll
        for (int c = 0; c < 16; ++c) {
          const float4* s4 = (const float4*)&x1[c * 132 + p0];
          float4 a4 = s4[0], b4 = s4[1], c4 = s4[2], d4 = s4[3];
          float xw[16] = {a4.x,a4.y,a4.z,a4.w, b4.x,b4.y,b4.z,b4.w,
                          c4.x,c4.y,c4.z,c4.w, d4.x,d4.y,d4.z,d4.w};
#pragma unroll
          for (int q = 0; q < 12; ++q)
#pragma unroll
            for (int k = 0; k < 5; ++k)
              acc[q] = fmaf(w2r[c * 5 + k], xw[q + k], acc[q]);
        }
        u32 pk[6];
#pragma unroll
        for (int q = 0; q < 6; ++q)
          pk[q] = f2bf(fmaxf(acc[2 * q], 0.0f)) | (f2bf(fmaxf(acc[2 * q + 1], 0.0f)) << 16);
        const int bu = (wv * 4 + jj) * 1920 + o2 * 60 + m * 6;  // even -> 8B aligned
        uint2* dq = (uint2*)(myslab32 + bu);
        dq[0] = make_uint2(pk[0], pk[1]);
        dq[1] = make_uint2(pk[2], pk[3]);
        dq[2] = make_uint2(pk[4], pk[5]);
      }
    }
    __syncthreads();  // slab writes drained & visible -> fc

    // ---------------- fc phase: MFMA, wave wv does output n-tiles wv, wv+4 ------
    {
      floatx4 acc0 = {bv0, bv0, bv0, bv0};
      floatx4 acc1 = {bv1, bv1, bv1, bv1};
      const u16* aPtr = myslab + (size_t)lr * 3840 + quad * 8;  // A: m=lane&15, k=quad*8+j
#pragma unroll 2
      for (int ks = 0; ks < 120; ++ks) {
        short8 a = *(const short8*)(aPtr + ks * 32);
        short8 b0 = b0p[ks * 64];
        short8 b1 = b1p[ks * 64];
        acc0 = __builtin_amdgcn_mfma_f32_16x16x32_bf16(a, b0, acc0, 0, 0, 0);
        acc1 = __builtin_amdgcn_mfma_f32_16x16x32_bf16(a, b1, acc1, 0, 0, 0);
      }
      // C/D: col = lane&15, row(node) = quad*4 + reg
#pragma unroll
      for (int r = 0; r < 4; ++r) {
        long node = node0 + quad * 4 + r;
        if (node < n) {
          xfc[node * 128 + c0] = acc0[r];
          xfc[node * 128 + c1] = acc1[r];
        }
      }
    }
  }
}

// Swizzle fc_w [128][3840] fp32 -> bf16 B-fragment-major layout:
// out[((nt*120 + ks)*64 + lane)] (uint4 = 8 bf16), element j =
//   fcw[nt*16 + (lane&15)][ks*32 + ((lane>>4)&3)*8 + j]
__global__ void k_cvt_fcw_sw(const float* __restrict__ fcw, uint4* __restrict__ out) {
  int gid = blockIdx.x * 256 + threadIdx.x;
  if (gid >= 8 * 120 * 64) return;
  int lane = gid & 63, tmp = gid >> 6;
  int ks = tmp % 120, nt = tmp / 120;
  int row = nt * 16 + (lane & 15);
  int k0 = ks * 32 + ((lane >> 4) & 3) * 8;
  const float* p = fcw + (size_t)row * 3840 + k0;
  float4 f0 = *(const float4*)p;
  float4 f1 = *(const float4*)(p + 4);
  uint4 o;
  o.x = f2bf(f0.x) | (f2bf(f0.y) << 16);
  o.y = f2bf(f0.z) | (f2bf(f0.w) << 16);
  o.z = f2bf(f1.x) | (f2bf(f1.y) << 16);
  o.w = f2bf(f1.z) | (f2bf(f1.w) << 16);
  out[gid] = o;
}

// ---------------------------------------------------------------------------
// GCN dense part, fused with self-loop + bias:
//   H[i][o]   = sum_k act(X[i][k]) * W[o][k]
//   Out[i][o] = bias[o] + dinv[i]^2 * H[i][o]   (self-loop term pre-seeded)
// Scatter then only handles the n real edges.
// ---------------------------------------------------------------------------
__global__ __launch_bounds__(256) void k_gcn_gemm(
    const float* __restrict__ X, const float* __restrict__ W,
    float* __restrict__ H, float* __restrict__ Out,
    const float* __restrict__ dinv, const float* __restrict__ bias,
    int n, int relu)
{
  __shared__ __align__(16) float sX[16 * 132];
  __shared__ __align__(8) u32 sW[128 * 66];
  const int t = threadIdx.x;
  const long node0 = (long)blockIdx.x * 16;
  for (int i = t; i < 8192; i += 256) {
    sW[(i >> 6) * 66 + (i & 63)] = f2bf(W[2 * i]) | (f2bf(W[2 * i + 1]) << 16);
  }
  for (int i = t; i < 2048; i += 256) {
    int j = i >> 7, k = i & 127;
    long node = node0 + j;
    float v = (node < n) ? X[node * 128 + k] : 0.0f;
    if (relu) v = fmaxf(v, 0.0f);
    sX[j * 132 + k] = v;
  }
  __syncthreads();
  const int og = t >> 3, jp = t & 7;  // 32 o-groups x 8 j-pairs
  float acc[4][2];
#pragma unroll
  for (int oo = 0; oo < 4; ++oo) { acc[oo][0] = 0.0f; acc[oo][1] = 0.0f; }
  for (int k = 0; k < 128; k += 4) {
    float wv[16];
#pragma unroll
    for (int oo = 0; oo < 4; ++oo) {
      uint2 wu = *(const uint2*)&sW[(og * 4 + oo) * 66 + (k >> 1)];
      wv[oo*4+0] = bflo(wu.x); wv[oo*4+1] = bfhi(wu.x);
      wv[oo*4+2] = bflo(wu.y); wv[oo*4+3] = bfhi(wu.y);
    }
#pragma unroll
    for (int jj = 0; jj < 2; ++jj) {
      const float4 x4 = *(const float4*)&sX[(jp * 2 + jj) * 132 + k];
#pragma unroll
      for (int oo = 0; oo < 4; ++oo)
        acc[oo][jj] = fmaf(wv[oo*4+0], x4.x, fmaf(wv[oo*4+1], x4.y,
                      fmaf(wv[oo*4+2], x4.z, fmaf(wv[oo*4+3], x4.w, acc[oo][jj]))));
    }
  }
#pragma unroll
  for (int jj = 0; jj < 2; ++jj) {
    long node = node0 + jp * 2 + jj;
    if (node < n) {
      float di = dinv[node];
      float d2 = di * di;
#pragma unroll
      for (int oo = 0; oo < 4; ++oo) {
        int o = og * 4 + oo;
        float v = acc[oo][jj];
        H[node * 128 + o] = v;
        Out[node * 128 + o] = bias[o] + d2 * v;
      }
    }
  }
}

// One wave per real edge; symmetric-norm message scatter (self-loops pre-seeded).
__global__ void k_scatter(const float* __restrict__ Hs, float* __restrict__ Out,
                          const int* __restrict__ src, const int* __restrict__ dst,
                          const float* __restrict__ dinv, int n)
{
  const int gid = blockIdx.x * blockDim.x + threadIdx.x;
  const int e = gid >> 6;
  const int lane = gid & 63;
  if (e >= n) return;
  const int s = src[e], d = dst[e];
  const float nrm = dinv[s] * dinv[d];
  const float2 v = *(const float2*)(Hs + (size_t)s * 128 + lane * 2);
  float* o = Out + (size_t)d * 128 + lane * 2;
  unsafeAtomicAdd(o, v.x * nrm);
  unsafeAtomicAdd(o + 1, v.y * nrm);
}

__global__ void k_fill1(float* p, int n) {
  int i = blockIdx.x * 256 + threadIdx.x; if (i < n) p[i] = 1.0f;
}
__global__ void k_deg(float* dinv, const int* __restrict__ dst, int n) {
  int i = blockIdx.x * 256 + threadIdx.x; if (i < n) unsafeAtomicAdd(&dinv[dst[i]], 1.0f);
}
__global__ void k_rsqrt(float* p, int n) {
  int i = blockIdx.x * 256 + threadIdx.x; if (i < n) p[i] = rsqrtf(p[i]);
}
__global__ void k_zero(float* p, int n) {
  int i = blockIdx.x * 256 + threadIdx.x; if (i < n) p[i] = 0.0f;
}

// LDS-staged pooling: pooled[batch[src[e]]] += X[e]
__global__ __launch_bounds__(256) void k_pool(const float* __restrict__ X,
    const int* __restrict__ src, const int* __restrict__ batch,
    float* __restrict__ pooled, int n)
{
  __shared__ float sAcc[64 * 128];
  for (int i = threadIdx.x; i < 8192; i += 256) sAcc[i] = 0.0f;
  __syncthreads();
  const int c = threadIdx.x & 127, half = threadIdx.x >> 7;
  for (int e = blockIdx.x * 2 + half; e < n; e += gridDim.x * 2) {
    int g = batch[src[e]];
    atomicAdd(&sAcc[g * 128 + c], X[(size_t)e * 128 + c]);
  }
  __syncthreads();
  for (int i = threadIdx.x; i < 8192; i += 256) unsafeAtomicAdd(&pooled[i], sAcc[i]);
}

// Final MLP head: relu(pooled @ fc1.T + b1) @ fc2.T + b2  (one block per graph)
__global__ __launch_bounds__(256) void k_mlp(const float* __restrict__ pooled,
    const float* __restrict__ f1w, const float* __restrict__ f1b,
    const float* __restrict__ f2w, const float* __restrict__ f2b,
    float* __restrict__ out)
{
  const int g = blockIdx.x, t = threadIdx.x;
  __shared__ float sP[128];
  __shared__ float sY[256];
  if (t < 128) sP[t] = pooled[g * 128 + t];
  __syncthreads();
  {
    const float* w = f1w + (size_t)t * 128;
    float a = f1b[t];
    for (int k = 0; k < 128; k += 4) {
      float4 w4 = *(const float4*)(w + k);
      a = fmaf(w4.x, sP[k], fmaf(w4.y, sP[k+1], fmaf(w4.z, sP[k+2], fmaf(w4.w, sP[k+3], a))));
    }
    sY[t] = fmaxf(a, 0.0f);
  }
  __syncthreads();
  if (t < 128) {
    const float* w = f2w + (size_t)t * 256;
    float a = f2b[t];
    for (int k = 0; k < 256; k += 4) {
      float4 w4 = *(const float4*)(w + k);
      a = fmaf(w4.x, sY[k], fmaf(w4.y, sY[k+1], fmaf(w4.z, sY[k+2], fmaf(w4.w, sY[k+3], a))));
    }
    out[g * 128 + t] = a;
  }
}

extern "C" void kernel_launch(void* const* d_in, const int* in_sizes, int n_in,
                              void* d_out, int out_size, void* d_ws, size_t ws_size,
                              hipStream_t stream) {
  const float* ea  = (const float*)d_in[0];
  const int* eidx  = (const int*)d_in[1];
  const int* batch = (const int*)d_in[2];
  const float* w1  = (const float*)d_in[4];
  const float* b1  = (const float*)d_in[5];
  const float* w2  = (const float*)d_in[6];
  const float* b2  = (const float*)d_in[7];
  const float* fcw = (const float*)d_in[8];
  const float* fcb = (const float*)d_in[9];
  const float* g1w = (const float*)d_in[10];
  const float* g1b = (const float*)d_in[11];
  const float* g2w = (const float*)d_in[12];
  const float* g2b = (const float*)d_in[13];
  const float* f1w = (const float*)d_in[14];
  const float* f1b = (const float*)d_in[15];
  const float* f2w = (const float*)d_in[16];
  const float* f2b = (const float*)d_in[17];

  const int n = in_sizes[0] / 720;   // 100000
  const int* src = eidx;             // edge_index[0]
  const int* dst = eidx + n;         // edge_index[1]

  // workspace layout (~156 MB)
  float* A      = (float*)d_ws;                 // [n,128]
  float* B      = A + (size_t)n * 128;          // [n,128]
  float* C      = B + (size_t)n * 128;          // [n,128]
  float* dinv   = C + (size_t)n * 128;          // [n]
  float* pooled = dinv + n;                     // [64,128]
  u32*  fcwsw   = (u32*)(pooled + 64 * 128);    // swizzled bf16 fc_w (245760 u32)
  // per-block conv2 slabs alias B+C (dead during k_convfc):
  // 768 blocks x 16*3840 bf16 = 94.4 MB; ends before dinv.
  u16* slab = (u16*)B;

  const int nb_n = (n + 255) / 256;
  const int ntiles = (n + 15) / 16;
  k_cvt_fcw_sw<<<(61440 + 255) / 256, 256, 0, stream>>>(fcw, (uint4*)fcwsw);
  k_fill1<<<nb_n, 256, 0, stream>>>(dinv, n);
  k_deg<<<nb_n, 256, 0, stream>>>(dinv, dst, n);
  k_rsqrt<<<nb_n, 256, 0, stream>>>(dinv, n);

  k_convfc<<<768, 256, 0, stream>>>(ea, w1, b1, w2, b2, fcwsw, fcb, slab, A, n, ntiles);

  // gcn1: H=B, Out=C (bias + self-loop seeded); scatter adds real edges
  k_gcn_gemm<<<(n + 15) / 16, 256, 0, stream>>>(A, g1w, B, C, dinv, g1b, n, 0);
  k_scatter<<<((size_t)n * 64 + 255) / 256, 256, 0, stream>>>(B, C, src, dst, dinv, n);

  // gcn2: X=relu(C), H=A, Out=B
  k_gcn_gemm<<<(n + 15) / 16, 256, 0, stream>>>(C, g2w, A, B, dinv, g2b, n, 1);
  k_scatter<<<((size_t)n * 64 + 255) / 256, 256, 0, stream>>>(A, B, src, dst, dinv, n);

  k_zero<<<(8192 + 255) / 256, 256, 0, stream>>>(pooled, 8192);
  k_pool<<<256, 256, 0, stream>>>(B, src, batch, pooled, n);
  k_mlp<<<64, 256, 0, stream>>>(pooled, f1w, f1b, f2w, f2b, (float*)d_out);
}

// Round 4
// 1836.598 us; speedup vs baseline: 4.2117x; 1.1389x over previous
//
#include <hip/hip_runtime.h>

typedef unsigned int u32;
typedef unsigned short u16;
typedef short short8 __attribute__((ext_vector_type(8)));   // 8 x bf16 (4 VGPRs)
typedef float floatx4 __attribute__((ext_vector_type(4)));  // MFMA accumulator

static __device__ __forceinline__ u32 f2bf(float f) {
  u32 u = __float_as_uint(f);
  return (u + 0x7fffu + ((u >> 16) & 1u)) >> 16;  // RNE bf16 bits
}

// ---------------------------------------------------------------------------
// MFMA conventions (verified rounds 1-3 fc): for mfma_f32_16x16x32_bf16(A,B,C):
//   A-frag: lane holds A[m = lane&15][k = quad*8+j], j=0..7 (one 16B load)
//   B-frag: lane holds B[k = quad*8+j][n = lane&15]  (value = W[n][k])
//   C/D   : col(n) = lane&15, row(m) = quad*4 + reg
// conv1: A=weights(m=cout), B=x0T(n=p), K=64 (k=tap*8+cin; tap>4,cin>5 zero)
// conv2: A=x1t(m=p),  B=weights(n=o), K=96 (k=tap*16+c; tap>4 zero)
// fc:    A=slab(m=node), B=fcwsw(n=outch), K=4096 (feat=o*128+p; p>119 zero)
// ---------------------------------------------------------------------------

#define X0T_ROWS 136   // u16[8] rows (16B); row r = x0 position r-2; rows >121 zero
#define X1T_ROWS 134   // u16[24] rows (48B); row r = x1 position r-2; rows >121 zero

__global__ __launch_bounds__(256, 4) void k_convfc(
    const float* __restrict__ ea,
    const u32* __restrict__ w1sw, const float* __restrict__ b1,
    const u32* __restrict__ w2sw, const float* __restrict__ b2,
    const u32* __restrict__ fcwsw, const float* __restrict__ fcb,
    u16* __restrict__ slab_base, float* __restrict__ xfc, int n, int ntiles)
{
  __shared__ u16 sX0T[4][X0T_ROWS * 8];    // per-wave
  __shared__ u16 sX1T[4][X1T_ROWS * 24];   // per-wave

  const int t = threadIdx.x, lane = t & 63, wv = t >> 6;
  const int quad = lane >> 4, lr = lane & 15;
  u16* __restrict__ x0 = sX0T[wv];
  u16* __restrict__ x1 = sX1T[wv];

  // zero both wave-private buffers once (halo rows / pad cols stay zero;
  // per-node writes only touch rows 2..121 of the real columns)
  for (int i = lane; i < X0T_ROWS * 4; i += 64) ((u32*)x0)[i] = 0;
  for (int i = lane; i < X1T_ROWS * 12; i += 64) ((u32*)x1)[i] = 0;

  // weights into registers
  short8 w1f[2], w2f[2][3];
#pragma unroll
  for (int kb = 0; kb < 2; ++kb) w1f[kb] = ((const short8*)w1sw)[kb * 64 + lane];
#pragma unroll
  for (int ot = 0; ot < 2; ++ot)
#pragma unroll
    for (int kb = 0; kb < 3; ++kb)
      w2f[ot][kb] = ((const short8*)w2sw)[(ot * 3 + kb) * 64 + lane];

  float b1r[4];
#pragma unroll
  for (int r = 0; r < 4; ++r) b1r[r] = b1[quad * 4 + r];
  const float bv20 = b2[lr], bv21 = b2[16 + lr];

  // fc setup
  const int c0 = wv * 16 + lr, c1 = (wv + 4) * 16 + lr;
  const float bv0 = fcb[c0], bv1 = fcb[c1];
  const short8* bw = (const short8*)fcwsw;
  const short8* b0p = bw + ((size_t)wv * 128) * 64 + lane;
  const short8* b1p = bw + ((size_t)(wv + 4) * 128) * 64 + lane;

  u16* myslab = slab_base + (size_t)blockIdx.x * (16 * 4096);
  const int j2base = wv * 4;

  for (int tile = blockIdx.x; tile < ntiles; tile += gridDim.x) {
    const long node0 = (long)tile * 16;
    __syncthreads();  // prior fc reads of slab complete before overwrite

    for (int jj = 0; jj < 4; ++jj) {
      const int j2 = j2base + jj;
      const long node = node0 + j2;
      // ---- stage ea -> x0T (transposed bf16, rows=pos+2, cols=cin) ----
      {
        int i = lane;
#pragma unroll
        for (int it = 0; it < 12; ++it) {
          if (i < 720) {
            int c = i / 120, p = i - c * 120;
            float v = (node < n) ? ea[node * 720 + i] : 0.0f;
            x0[(p + 2) * 8 + c] = (u16)f2bf(v);
          }
          i += 64;
        }
      }
      // ---- conv1 via MFMA: per p-tile, 2 k-blocks ----
#pragma unroll
      for (int pt = 0; pt < 8; ++pt) {
        const int row0 = pt * 16 + lr;
        short8 bx0 = *(const short8*)&x0[(row0 + quad) * 8];       // taps 0..3
        short8 bx1 = *(const short8*)&x0[(row0 + 4 + quad) * 8];   // taps 4..7 (5..7 zero-W)
        floatx4 a1 = {b1r[0], b1r[1], b1r[2], b1r[3]};
        a1 = __builtin_amdgcn_mfma_f32_16x16x32_bf16(w1f[0], bx0, a1, 0, 0, 0);
        a1 = __builtin_amdgcn_mfma_f32_16x16x32_bf16(w1f[1], bx1, a1, 0, 0, 0);
        // store x1t[p+2][cout quad*4..+3], only valid positions p<120
        if (pt < 7 || lr < 8) {
          u32 lo = f2bf(fmaxf(a1[0], 0.0f)) | (f2bf(fmaxf(a1[1], 0.0f)) << 16);
          u32 hi = f2bf(fmaxf(a1[2], 0.0f)) | (f2bf(fmaxf(a1[3], 0.0f)) << 16);
          *(uint2*)&x1[(row0 + 2) * 24 + quad * 4] = make_uint2(lo, hi);
        }
      }
      // ---- conv2 via MFMA -> slab (feature order o*128+p) ----
#pragma unroll
      for (int pt = 0; pt < 8; ++pt) {
        const int row0 = pt * 16 + lr;
        const int tq = quad >> 1, cq = (quad & 1) * 8;
        short8 ax0 = *(const short8*)&x1[(row0 + tq) * 24 + cq];       // taps 0,1
        short8 ax1 = *(const short8*)&x1[(row0 + 2 + tq) * 24 + cq];   // taps 2,3
        short8 ax2 = *(const short8*)&x1[(row0 + 4 + tq) * 24 + cq];   // taps 4,5(zero-W)
#pragma unroll
        for (int ot = 0; ot < 2; ++ot) {
          const float bb = ot ? bv21 : bv20;
          floatx4 a2 = {bb, bb, bb, bb};
          a2 = __builtin_amdgcn_mfma_f32_16x16x32_bf16(ax0, w2f[ot][0], a2, 0, 0, 0);
          a2 = __builtin_amdgcn_mfma_f32_16x16x32_bf16(ax1, w2f[ot][1], a2, 0, 0, 0);
          a2 = __builtin_amdgcn_mfma_f32_16x16x32_bf16(ax2, w2f[ot][2], a2, 0, 0, 0);
          u32 lo = f2bf(fmaxf(a2[0], 0.0f)) | (f2bf(fmaxf(a2[1], 0.0f)) << 16);
          u32 hi = f2bf(fmaxf(a2[2], 0.0f)) | (f2bf(fmaxf(a2[3], 0.0f)) << 16);
          const int fi = j2 * 4096 + (ot * 16 + lr) * 128 + pt * 16 + quad * 4;
          *(uint2*)(myslab + fi) = make_uint2(lo, hi);
        }
      }
    }
    __syncthreads();  // slab visible to all waves

    // ---- fc phase: MFMA over K=4096, wave wv does n-tiles wv and wv+4 ----
    {
      floatx4 acc0 = {bv0, bv0, bv0, bv0};
      floatx4 acc1 = {bv1, bv1, bv1, bv1};
      const u16* aPtr = myslab + (size_t)lr * 4096 + quad * 8;
#pragma unroll 2
      for (int ks = 0; ks < 128; ++ks) {
        short8 a = *(const short8*)(aPtr + ks * 32);
        short8 bb0 = b0p[ks * 64];
        short8 bb1 = b1p[ks * 64];
        acc0 = __builtin_amdgcn_mfma_f32_16x16x32_bf16(a, bb0, acc0, 0, 0, 0);
        acc1 = __builtin_amdgcn_mfma_f32_16x16x32_bf16(a, bb1, acc1, 0, 0, 0);
      }
#pragma unroll
      for (int r = 0; r < 4; ++r) {
        long node = node0 + quad * 4 + r;
        if (node < n) {
          xfc[node * 128 + c0] = acc0[r];
          xfc[node * 128 + c1] = acc1[r];
        }
      }
    }
  }
}

// ---------------------------------------------------------------------------
// Merged prep: fcwsw / g1wsw / g2wsw / w1sw / w2sw swizzles + dinv=1 + pooled=0
// ---------------------------------------------------------------------------
__global__ void k_prep(const float* __restrict__ fcw, const float* __restrict__ g1w,
                       const float* __restrict__ g2w, const float* __restrict__ w1,
                       const float* __restrict__ w2,
                       uint4* __restrict__ fcwsw, uint4* __restrict__ g1wsw,
                       uint4* __restrict__ g2wsw, uint4* __restrict__ w1sw,
                       uint4* __restrict__ w2sw,
                       float* __restrict__ dinv, float* __restrict__ pooled, int n)
{
  int gid = blockIdx.x * 256 + threadIdx.x;
  if (gid < 65536) {  // fcwsw: entry = (nt*128+ks)*64+lane, feat k = o*128+p
    int e = gid, lane = e & 63, t2 = e >> 6, ks = t2 & 127, nt = t2 >> 7;
    int col = nt * 16 + (lane & 15);
    int k0 = ks * 32 + ((lane >> 4) & 3) * 8;
    u32 pk[4];
#pragma unroll
    for (int h = 0; h < 4; ++h) {
      u32 v01[2];
#pragma unroll
      for (int g = 0; g < 2; ++g) {
        int k = k0 + h * 2 + g;
        int o = k >> 7, p = k & 127;
        float v = (p < 120) ? fcw[(size_t)col * 3840 + o * 120 + p] : 0.0f;
        v01[g] = f2bf(v);
      }
      pk[h] = v01[0] | (v01[1] << 16);
    }
    fcwsw[e] = make_uint4(pk[0], pk[1], pk[2], pk[3]);
    return;
  }
  gid -= 65536;
  if (gid < 4096) {  // g1wsw / g2wsw: entry = (nt*4+kb)*64+lane
    const float* gw = (gid < 2048) ? g1w : g2w;
    uint4* out = (gid < 2048) ? g1wsw : g2wsw;
    int e = gid & 2047, lane = e & 63;
    int col = (e >> 8) * 16 + (lane & 15);            // nt = e>>8 (t2>>2)
    int k0 = ((e >> 6) & 3) * 32 + ((lane >> 4) & 3) * 8;
    u32 pk[4];
#pragma unroll
    for (int h = 0; h < 4; ++h)
      pk[h] = f2bf(gw[(size_t)col * 128 + k0 + h * 2]) |
              (f2bf(gw[(size_t)col * 128 + k0 + h * 2 + 1]) << 16);
    out[e] = make_uint4(pk[0], pk[1], pk[2], pk[3]);
    return;
  }
  gid -= 4096;
  if (gid < 128) {  // w1sw: entry = kb*64+lane; k = tap*8+cin
    int e = gid, lane = e & 63, kb = e >> 6, cout = lane & 15;
    int k0 = kb * 32 + ((lane >> 4) & 3) * 8;
    u32 pk[4];
#pragma unroll
    for (int h = 0; h < 4; ++h) {
      u32 v01[2];
#pragma unroll
      for (int g = 0; g < 2; ++g) {
        int k = k0 + h * 2 + g, tap = k >> 3, cin = k & 7;
        float v = (tap < 5 && cin < 6) ? w1[cout * 30 + cin * 5 + tap] : 0.0f;
        v01[g] = f2bf(v);
      }
      pk[h] = v01[0] | (v01[1] << 16);
    }
    w1sw[e] = make_uint4(pk[0], pk[1], pk[2], pk[3]);
    return;
  }
  gid -= 128;
  if (gid < 384) {  // w2sw: entry = (ot*3+kb)*64+lane; k = tap*16+c
    int e = gid, lane = e & 63, t2 = e >> 6;
    int kb = t2 % 3, ot = t2 / 3;
    int o = ot * 16 + (lane & 15);
    int k0 = kb * 32 + ((lane >> 4) & 3) * 8;
    u32 pk[4];
#pragma unroll
    for (int h = 0; h < 4; ++h) {
      u32 v01[2];
#pragma unroll
      for (int g = 0; g < 2; ++g) {
        int k = k0 + h * 2 + g, tap = k >> 4, c = k & 15;
        float v = (tap < 5) ? w2[o * 80 + c * 5 + tap] : 0.0f;
        v01[g] = f2bf(v);
      }
      pk[h] = v01[0] | (v01[1] << 16);
    }
    w2sw[e] = make_uint4(pk[0], pk[1], pk[2], pk[3]);
    return;
  }
  gid -= 384;
  if (gid < n) { dinv[gid] = 1.0f; return; }
  gid -= n;
  if (gid < 8192) pooled[gid] = 0.0f;
}

// ---------------------------------------------------------------------------
// GCN dense layer via MFMA, fused self-loop + bias:
//   H[i][o] = sum_k act(X[i][k]) * W[o][k]
//   Out[i][o] = bias[o] + dinv[i]^2 * H[i][o]
// ---------------------------------------------------------------------------
__global__ __launch_bounds__(256) void k_gcn_gemm(
    const float* __restrict__ X, const u32* __restrict__ wsw,
    const float* __restrict__ bias, const float* __restrict__ dinv,
    float* __restrict__ H, float* __restrict__ Out, int n, int relu)
{
  __shared__ __align__(16) u16 sA[16 * 136];
  __shared__ float sDi[16];
  const int t = threadIdx.x;
  const long node0 = (long)blockIdx.x * 16;
  {
    int nd = t >> 4, k0 = (t & 15) * 8;
    long node = node0 + nd;
    float v[8];
    if (node < n) {
      float4 f0 = *(const float4*)&X[node * 128 + k0];
      float4 f1 = *(const float4*)&X[node * 128 + k0 + 4];
      v[0]=f0.x; v[1]=f0.y; v[2]=f0.z; v[3]=f0.w; v[4]=f1.x; v[5]=f1.y; v[6]=f1.z; v[7]=f1.w;
      if (relu) {
#pragma unroll
        for (int i = 0; i < 8; ++i) v[i] = fmaxf(v[i], 0.0f);
      }
    } else {
#pragma unroll
      for (int i = 0; i < 8; ++i) v[i] = 0.0f;
    }
    u32 pk[4];
#pragma unroll
    for (int h = 0; h < 4; ++h) pk[h] = f2bf(v[2*h]) | (f2bf(v[2*h+1]) << 16);
    *(uint4*)&sA[nd * 136 + k0] = make_uint4(pk[0], pk[1], pk[2], pk[3]);
    if (t < 16) sDi[t] = (node0 + t < n) ? dinv[node0 + t] : 0.0f;
  }
  __syncthreads();
  const int lane = t & 63, wv = t >> 6, quad = lane >> 4, lr = lane & 15;
  short8 af[4];
#pragma unroll
  for (int kb = 0; kb < 4; ++kb)
    af[kb] = *(const short8*)&sA[lr * 136 + kb * 32 + quad * 8];
#pragma unroll
  for (int h = 0; h < 2; ++h) {
    const int nt = wv + h * 4;
    const short8* bp = ((const short8*)wsw) + (nt * 4) * 64 + lane;
    floatx4 acc = {0.0f, 0.0f, 0.0f, 0.0f};
#pragma unroll
    for (int kb = 0; kb < 4; ++kb)
      acc = __builtin_amdgcn_mfma_f32_16x16x32_bf16(af[kb], bp[kb * 64], acc, 0, 0, 0);
    const int col = nt * 16 + lr;
    const float bcol = bias[col];
#pragma unroll
    for (int r = 0; r < 4; ++r) {
      long node = node0 + quad * 4 + r;
      if (node < n) {
        float hv = acc[r];
        float di = sDi[quad * 4 + r];
        H[node * 128 + col] = hv;
        Out[node * 128 + col] = bcol + di * di * hv;
      }
    }
  }
}

// One wave per real edge; symmetric-norm message scatter (self-loops pre-seeded).
__global__ void k_scatter(const float* __restrict__ Hs, float* __restrict__ Out,
                          const int* __restrict__ src, const int* __restrict__ dst,
                          const float* __restrict__ dinv, int n)
{
  const int gid = blockIdx.x * blockDim.x + threadIdx.x;
  const int e = gid >> 6;
  const int lane = gid & 63;
  if (e >= n) return;
  const int s = src[e], d = dst[e];
  const float nrm = dinv[s] * dinv[d];
  const float2 v = *(const float2*)(Hs + (size_t)s * 128 + lane * 2);
  float* o = Out + (size_t)d * 128 + lane * 2;
  unsafeAtomicAdd(o, v.x * nrm);
  unsafeAtomicAdd(o + 1, v.y * nrm);
}

__global__ void k_deg(float* dinv, const int* __restrict__ dst, int n) {
  int i = blockIdx.x * 256 + threadIdx.x; if (i < n) unsafeAtomicAdd(&dinv[dst[i]], 1.0f);
}
__global__ void k_rsqrt(float* p, int n) {
  int i = blockIdx.x * 256 + threadIdx.x; if (i < n) p[i] = rsqrtf(p[i]);
}

// LDS-staged pooling: pooled[batch[src[e]]] += X[e]
__global__ __launch_bounds__(256) void k_pool(const float* __restrict__ X,
    const int* __restrict__ src, const int* __restrict__ batch,
    float* __restrict__ pooled, int n)
{
  __shared__ float sAcc[64 * 128];
  for (int i = threadIdx.x; i < 8192; i += 256) sAcc[i] = 0.0f;
  __syncthreads();
  const int c = threadIdx.x & 127, half = threadIdx.x >> 7;
  for (int e = blockIdx.x * 2 + half; e < n; e += gridDim.x * 2) {
    int g = batch[src[e]];
    atomicAdd(&sAcc[g * 128 + c], X[(size_t)e * 128 + c]);
  }
  __syncthreads();
  for (int i = threadIdx.x; i < 8192; i += 256) unsafeAtomicAdd(&pooled[i], sAcc[i]);
}

// Final MLP head: relu(pooled @ fc1.T + b1) @ fc2.T + b2  (one block per graph)
__global__ __launch_bounds__(256) void k_mlp(const float* __restrict__ pooled,
    const float* __restrict__ f1w, const float* __restrict__ f1b,
    const float* __restrict__ f2w, const float* __restrict__ f2b,
    float* __restrict__ out)
{
  const int g = blockIdx.x, t = threadIdx.x;
  __shared__ float sP[128];
  __shared__ float sY[256];
  if (t < 128) sP[t] = pooled[g * 128 + t];
  __syncthreads();
  {
    const float* w = f1w + (size_t)t * 128;
    float a = f1b[t];
    for (int k = 0; k < 128; k += 4) {
      float4 w4 = *(const float4*)(w + k);
      a = fmaf(w4.x, sP[k], fmaf(w4.y, sP[k+1], fmaf(w4.z, sP[k+2], fmaf(w4.w, sP[k+3], a))));
    }
    sY[t] = fmaxf(a, 0.0f);
  }
  __syncthreads();
  if (t < 128) {
    const float* w = f2w + (size_t)t * 256;
    float a = f2b[t];
    for (int k = 0; k < 256; k += 4) {
      float4 w4 = *(const float4*)(w + k);
      a = fmaf(w4.x, sY[k], fmaf(w4.y, sY[k+1], fmaf(w4.z, sY[k+2], fmaf(w4.w, sY[k+3], a))));
    }
    out[g * 128 + t] = a;
  }
}

extern "C" void kernel_launch(void* const* d_in, const int* in_sizes, int n_in,
                              void* d_out, int out_size, void* d_ws, size_t ws_size,
                              hipStream_t stream) {
  const float* ea  = (const float*)d_in[0];
  const int* eidx  = (const int*)d_in[1];
  const int* batch = (const int*)d_in[2];
  const float* w1  = (const float*)d_in[4];
  const float* b1  = (const float*)d_in[5];
  const float* w2  = (const float*)d_in[6];
  const float* b2  = (const float*)d_in[7];
  const float* fcw = (const float*)d_in[8];
  const float* fcb = (const float*)d_in[9];
  const float* g1w = (const float*)d_in[10];
  const float* g1b = (const float*)d_in[11];
  const float* g2w = (const float*)d_in[12];
  const float* g2b = (const float*)d_in[13];
  const float* f1w = (const float*)d_in[14];
  const float* f1b = (const float*)d_in[15];
  const float* f2w = (const float*)d_in[16];
  const float* f2b = (const float*)d_in[17];

  const int n = in_sizes[0] / 720;   // 100000
  const int* src = eidx;             // edge_index[0]
  const int* dst = eidx + n;         // edge_index[1]

  // workspace layout (~155.3 MB)
  float* A      = (float*)d_ws;                   // [n,128]
  float* B      = A + (size_t)n * 128;            // [n,128]
  float* C      = B + (size_t)n * 128;            // [n,128]
  float* dinv   = C + (size_t)n * 128;            // [n]
  float* pooled = dinv + n;                       // [64,128]
  u32*   fcwsw  = (u32*)(pooled + 64 * 128);      // 65536 uint4 = 1 MB
  u32*   g1wsw  = fcwsw + 65536 * 4;              // 2048 uint4
  u32*   g2wsw  = g1wsw + 2048 * 4;               // 2048 uint4
  u32*   w1sw   = g2wsw + 2048 * 4;               // 128 uint4
  u32*   w2sw   = w1sw + 128 * 4;                 // 384 uint4
  // per-block conv2/fc slabs alias B..C (dead during k_convfc):
  // 768 blocks x 16*4096 bf16 = 96 MiB <= 102.4 MB
  u16* slab = (u16*)B;

  const int nb_n = (n + 255) / 256;
  const int ntiles = (n + 15) / 16;
  const int prep_total = 65536 + 2048 + 2048 + 128 + 384 + n + 8192;
  k_prep<<<(prep_total + 255) / 256, 256, 0, stream>>>(
      fcw, g1w, g2w, w1, w2, (uint4*)fcwsw, (uint4*)g1wsw, (uint4*)g2wsw,
      (uint4*)w1sw, (uint4*)w2sw, dinv, pooled, n);
  k_deg<<<nb_n, 256, 0, stream>>>(dinv, dst, n);
  k_rsqrt<<<nb_n, 256, 0, stream>>>(dinv, n);

  k_convfc<<<768, 256, 0, stream>>>(ea, w1sw, b1, w2sw, b2, fcwsw, fcb, slab, A, n, ntiles);

  // gcn1: X=A -> H=B, Out=C (bias + self-loop seeded); scatter adds real edges
  k_gcn_gemm<<<(n + 15) / 16, 256, 0, stream>>>(A, g1wsw, g1b, dinv, B, C, n, 0);
  k_scatter<<<((size_t)n * 64 + 255) / 256, 256, 0, stream>>>(B, C, src, dst, dinv, n);

  // gcn2: X=relu(C) -> H=A, Out=B
  k_gcn_gemm<<<(n + 15) / 16, 256, 0, stream>>>(C, g2wsw, g2b, dinv, A, B, n, 1);
  k_scatter<<<((size_t)n * 64 + 255) / 256, 256, 0, stream>>>(A, B, src, dst, dinv, n);

  k_pool<<<256, 256, 0, stream>>>(B, src, batch, pooled, n);
  k_mlp<<<64, 256, 0, stream>>>(pooled, f1w, f1b, f2w, f2b, (float*)d_out);
}